// Round 7
// baseline (150.068 us; speedup 1.0000x reference)
//
#include <hip/hip_runtime.h>
#include <hip/hip_bf16.h>
#include <stdint.h>

// NonLocalBlock, fp32 in/out. B=4, N=4096, C=256, D=32.
// v13: revert v12's xres register prefetch — holding 16 VGPRs live across
// the main loop pushed the allocator (targeting 64 VGPR) into scratch
// spills: FETCH 87 MB / WRITE 124 MB of spill traffic, attn 10us -> ~50us.
// x is now read directly in the epilogue (post-barrier) via float4.
// Keeps v12's float4 epilogue retile (registers only live after accO dies)
// and float4 out stores. Main loop = v10 (fp16 q/k, one f16 MFMA for S^T,
// bf16 P/V, barrier-free). ~88 us of total dur is harness ws-poison fill.

typedef __attribute__((ext_vector_type(8))) short bf16x8;
typedef __attribute__((ext_vector_type(4))) short bf16x4;
typedef __attribute__((ext_vector_type(8))) _Float16 f16x8;
typedef __attribute__((ext_vector_type(4))) float f32x4;
typedef unsigned short ushort_t;

static __device__ __forceinline__ ushort_t f2bf(float f) {
    __hip_bfloat16 h = __float2bfloat16(f);
    return __builtin_bit_cast(ushort_t, h);
}
static __device__ __forceinline__ float bf2f(ushort_t u) {
    return __bfloat162float(__builtin_bit_cast(__hip_bfloat16, u));
}
static __device__ __forceinline__ ushort_t f2h(float f) {
    _Float16 h = (_Float16)f;            // RNE v_cvt_f16_f32
    return __builtin_bit_cast(ushort_t, h);
}
// truncation split: hi = top 16 bits (no rounding), residual w-hi is exact,
// lo = RNE bf16 of residual.
static __device__ __forceinline__ void tsplit(float w, ushort_t& hi, ushort_t& lo) {
    uint32_t b = __builtin_bit_cast(uint32_t, w);
    hi = (ushort_t)(b >> 16);
    float hf = __builtin_bit_cast(float, b & 0xFFFF0000u);
    lo = f2bf(w - hf);
}

static __device__ __forceinline__ f32x4 mfma16bf(bf16x4 a, bf16x4 b, f32x4 c) {
#if __has_builtin(__builtin_amdgcn_mfma_f32_16x16x16bf16_1k)
    return __builtin_amdgcn_mfma_f32_16x16x16bf16_1k(a, b, c, 0, 0, 0);
#else
    f32x4 d;
    asm("v_mfma_f32_16x16x16_bf16 %0, %1, %2, %3"
        : "=v"(d) : "v"(a), "v"(b), "v"(c));
    return d;
#endif
}

static __device__ __forceinline__ float fexp2(float x) {
#if __has_builtin(__builtin_amdgcn_exp2f)
    return __builtin_amdgcn_exp2f(x);
#else
    return exp2f(x);
#endif
}

#define NROWS 16384
#define NTOK  4096
#define QKS   40   // x-staging LDS row stride (ushorts): 80 B, 16B-aligned
#define LOG2E 1.44269504088896340736f

// ---------------- K1: QKV projection via split-bf16 MFMA ----------------
// 32 rows/block, grid 512 (2 blocks/CU). Wave w: row-group w&1, col-groups
// (w>>1)+{0,2,4}. W fp32 read per-lane (L1/L2-hot), truncation-split in regs.
// q output pre-scaled by log2(e); q and k stored fp16, v bf16 transposed.
__global__ __launch_bounds__(256) void qkv_kernel(
    const float* __restrict__ x,
    const float* __restrict__ Wf, const float* __restrict__ Wg,
    const float* __restrict__ Wh,
    ushort_t* __restrict__ qh,   // fp16 [b*n][32], pre-scaled by log2(e)
    ushort_t* __restrict__ kf,   // fp16 [b*n][32]
    ushort_t* __restrict__ vT)   // bf16 [b][d][m] = [4][32][4096]
{
    __shared__ __align__(16) ushort_t xh[32 * QKS];
    __shared__ __align__(16) ushort_t xl[32 * QKS];

    const int tid  = threadIdx.x;
    const int wave = tid >> 6;
    const int lane = tid & 63;
    const int ln15 = lane & 15;
    const int quad = lane >> 4;
    const int row0 = blockIdx.x * 32;
    const int rg     = wave & 1;
    const int cgbase = wave >> 1;
    const int r  = tid >> 3;        // staging row 0..31
    const int pp = (tid & 7) * 4;   // staging col (floats)

    f32x4 acc[3];
    #pragma unroll
    for (int ci = 0; ci < 3; ++ci) acc[ci] = (f32x4){0.f, 0.f, 0.f, 0.f};

    float4 xa = *reinterpret_cast<const float4*>(&x[(row0 + r) * 256 + pp]);

    for (int k0 = 0; k0 < 256; k0 += 32) {
        // B fragments: read W fp32 directly, truncation-split in registers
        bf16x8 bh[3], bl[3];
        #pragma unroll
        for (int ci = 0; ci < 3; ++ci) {
            int cg = cgbase + ci * 2;
            const float* Wsrc = (cg < 2) ? Wf : (cg < 4) ? Wg : Wh;
            int c = (cg & 1) * 16 + ln15;
            ushort_t hv8[8], lv8[8];
            #pragma unroll
            for (int j = 0; j < 8; ++j) {
                float w = Wsrc[(k0 + quad * 8 + j) * 32 + c];
                tsplit(w, hv8[j], lv8[j]);
            }
            bh[ci] = *reinterpret_cast<bf16x8*>(hv8);
            bl[ci] = *reinterpret_cast<bf16x8*>(lv8);
        }
        // split current x chunk
        float fv[4];
        *reinterpret_cast<float4*>(fv) = xa;
        ushort_t hv[4], lv[4];
        #pragma unroll
        for (int j = 0; j < 4; ++j) tsplit(fv[j], hv[j], lv[j]);
        __syncthreads();
        *reinterpret_cast<uint2*>(&xh[r * QKS + pp]) = *reinterpret_cast<uint2*>(hv);
        *reinterpret_cast<uint2*>(&xl[r * QKS + pp]) = *reinterpret_cast<uint2*>(lv);
        __syncthreads();
        if (k0 < 224)
            xa = *reinterpret_cast<const float4*>(&x[(row0 + r) * 256 + k0 + 32 + pp]);

        const bf16x8 ah = *reinterpret_cast<const bf16x8*>(
            &xh[(rg * 16 + ln15) * QKS + quad * 8]);
        const bf16x8 al = *reinterpret_cast<const bf16x8*>(
            &xl[(rg * 16 + ln15) * QKS + quad * 8]);
        #pragma unroll
        for (int ci = 0; ci < 3; ++ci) {
            acc[ci] = __builtin_amdgcn_mfma_f32_16x16x32_bf16(ah, bh[ci], acc[ci], 0, 0, 0);
            acc[ci] = __builtin_amdgcn_mfma_f32_16x16x32_bf16(al, bh[ci], acc[ci], 0, 0, 0);
            acc[ci] = __builtin_amdgcn_mfma_f32_16x16x32_bf16(ah, bl[ci], acc[ci], 0, 0, 0);
        }
    }

    #pragma unroll
    for (int ci = 0; ci < 3; ++ci) {
        int cg = cgbase + ci * 2;
        int cc = (cg & 1) * 16 + ln15;
        int rowb = row0 + rg * 16 + quad * 4;
        if (cg < 2) {
            #pragma unroll
            for (int rr = 0; rr < 4; ++rr)
                qh[(rowb + rr) * 32 + cc] = f2h(acc[ci][rr] * LOG2E);
        } else if (cg < 4) {
            #pragma unroll
            for (int rr = 0; rr < 4; ++rr)
                kf[(rowb + rr) * 32 + cc] = f2h(acc[ci][rr]);
        } else {
            // V pre-transposed: vT[b][d=cc][m], m = rowb..rowb+3 (same batch)
            int bb = row0 >> 12;
            int m  = (row0 & 4095) + rg * 16 + quad * 4;
            ushort4 h4;
            h4.x = f2bf(acc[ci][0]);
            h4.y = f2bf(acc[ci][1]);
            h4.z = f2bf(acc[ci][2]);
            h4.w = f2bf(acc[ci][3]);
            *reinterpret_cast<ushort4*>(&vT[bb * 131072 + cc * 4096 + m]) = h4;
        }
    }
}

// ---------------- K2: fused attention + output projection ----------------
// Grid 256 = 4 batches x 64 rowtiles, 1024 threads (16 waves, 4 waves/SIMD).
// Main loop identical to v10 (barrier-free, register-resident; one f16 MFMA
// for S^T, two bf16 16x16x16 MFMAs for PV per tile). Epilogue: cross-wave
// O^T reduce, then out-proj tiled 4 rows x 4 cols per thread with float4
// LDS reads of Os/wv, float4 x loads and float4 out stores (no long-lived
// registers across the main loop — v12's xres prefetch caused spills).
__global__ __launch_bounds__(1024, 4) void attn_kernel(
    const ushort_t* __restrict__ qhg,
    const ushort_t* __restrict__ kfg,
    const ushort_t* __restrict__ vT,
    const float* __restrict__ Wv, const float* __restrict__ x,
    const float* __restrict__ gamma, float* __restrict__ out)
{
    __shared__ float Ored[8][32][65];   // [slot][d][n], stride 65
    __shared__ float Lred[8][64];
    __shared__ float wv[8192];          // Wv [32][256]
    __shared__ float Os[64][36];        // O [n][d], stride 36 (144 B, 16B-aligned)
    __shared__ float linv[64];

    const int tid  = threadIdx.x;
    const int wave = tid >> 6;          // 0..15
    const int lane = tid & 63;
    const int ln15 = lane & 15;
    const int quad = lane >> 4;

    const int b    = blockIdx.x >> 6;
    const int n0   = (blockIdx.x & 63) * 64;
    const int base = b * NTOK;
    const int bb   = b * 131072;        // vT batch offset

    // K fragments in registers (B-operand of S^T): K[n=t*16+ln15][c=quad*8..+7]
    f16x8 khf[4];
    #pragma unroll
    for (int t = 0; t < 4; ++t)
        khf[t] = *reinterpret_cast<const f16x8*>(
            &kfg[(base + n0 + t * 16 + ln15) * 32 + quad * 8]);

    // stage Wv while the main loop runs (no barrier until epilogue)
    #pragma unroll
    for (int i = 0; i < 8; ++i) wv[tid + i * 1024] = Wv[tid + i * 1024];

    f32x4 accO[2][4];   // [s01 = d-tile][t = n-tile]
    #pragma unroll
    for (int s01 = 0; s01 < 2; ++s01)
        #pragma unroll
        for (int t = 0; t < 4; ++t)
            accO[s01][t] = (f32x4){0.f, 0.f, 0.f, 0.f};
    float lacc[4] = {0.f, 0.f, 0.f, 0.f};

    // per-wave m walk: m = it*256 + wave*16 + {0..15}, it = 0..15
    const int mbase = wave * 16;
    const ushort_t* qp  = qhg + (size_t)(base + mbase + ln15) * 32 + quad * 8;
    const ushort_t* vp0 = vT + bb + ln15 * 4096 + mbase + quad * 4;
    const ushort_t* vp1 = vp0 + 16 * 4096;

    f16x8  qf  = *reinterpret_cast<const f16x8*>(qp);    // A: Q[m=ln15][c]
    bf16x4 va0 = *reinterpret_cast<const bf16x4*>(vp0);  // A: V^T[d=ln15][m']
    bf16x4 va1 = *reinterpret_cast<const bf16x4*>(vp1);  // A: V^T[d=16+ln15][m']

    for (int it = 0; it < 16; ++it) {
        qp  += 256 * 32;
        vp0 += 256;
        vp1 += 256;
        // prefetch next iter (it=15 reads past the 3 MB region but stays well
        // inside the 256 MB workspace; values unused)
        f16x8  nqf  = *reinterpret_cast<const f16x8*>(qp);
        bf16x4 nva0 = *reinterpret_cast<const bf16x4*>(vp0);
        bf16x4 nva1 = *reinterpret_cast<const bf16x4*>(vp1);

        #pragma unroll
        for (int t = 0; t < 4; ++t) {
            // S^T[m'][n] for n-tile t; lane: m'=quad*4+rr, n=t*16+ln15
            f32x4 s = __builtin_amdgcn_mfma_f32_16x16x32_f16(
                qf, khf[t], (f32x4){0.f, 0.f, 0.f, 0.f}, 0, 0, 0);

            float p0 = fexp2(s[0]);
            float p1 = fexp2(s[1]);
            float p2 = fexp2(s[2]);
            float p3 = fexp2(s[3]);
            lacc[t] += (p0 + p1) + (p2 + p3);

            ushort_t pu[4];
            pu[0] = f2bf(p0);
            pu[1] = f2bf(p1);
            pu[2] = f2bf(p2);
            pu[3] = f2bf(p3);
            const bf16x4 pb = *reinterpret_cast<bf16x4*>(pu);  // B: P^T[m'][n]

            accO[0][t] = mfma16bf(va0, pb, accO[0][t]);
            accO[1][t] = mfma16bf(va1, pb, accO[1][t]);
        }
        qf = nqf; va0 = nva0; va1 = nva1;
    }

    // ---- cross-wave reduction ----
    // lane holds O^T[d = s01*16 + quad*4 + rr][n = t*16 + ln15]
    float lr[4];
    #pragma unroll
    for (int t = 0; t < 4; ++t) {
        float v = lacc[t];
        v += __shfl_xor(v, 16);
        v += __shfl_xor(v, 32);
        lr[t] = v;
    }
    if (wave < 8) {
        #pragma unroll
        for (int s01 = 0; s01 < 2; ++s01)
            #pragma unroll
            for (int t = 0; t < 4; ++t)
                #pragma unroll
                for (int rr = 0; rr < 4; ++rr)
                    Ored[wave][s01 * 16 + quad * 4 + rr][t * 16 + ln15] = accO[s01][t][rr];
        if (quad == 0) {
            #pragma unroll
            for (int t = 0; t < 4; ++t) Lred[wave][t * 16 + ln15] = lr[t];
        }
    }
    __syncthreads();
    if (wave >= 8) {
        const int ws = wave - 8;
        #pragma unroll
        for (int s01 = 0; s01 < 2; ++s01)
            #pragma unroll
            for (int t = 0; t < 4; ++t)
                #pragma unroll
                for (int rr = 0; rr < 4; ++rr)
                    Ored[ws][s01 * 16 + quad * 4 + rr][t * 16 + ln15] += accO[s01][t][rr];
        if (quad == 0) {
            #pragma unroll
            for (int t = 0; t < 4; ++t) Lred[ws][t * 16 + ln15] += lr[t];
        }
    }
    __syncthreads();

    // O[n][d] = sum over 8 slots; 1/l
    #pragma unroll
    for (int i = 0; i < 2; ++i) {
        int idx = i * 1024 + tid;     // 0..2047
        int d = idx & 31;
        int n = idx >> 5;
        float v = (Ored[0][d][n] + Ored[1][d][n]) + (Ored[2][d][n] + Ored[3][d][n])
                + (Ored[4][d][n] + Ored[5][d][n]) + (Ored[6][d][n] + Ored[7][d][n]);
        Os[n][d] = v;
    }
    if (tid < 64) {
        float s = (Lred[0][tid] + Lred[1][tid]) + (Lred[2][tid] + Lred[3][tid])
                + (Lred[4][tid] + Lred[5][tid]) + (Lred[6][tid] + Lred[7][tid]);
        linv[tid] = 1.0f / s;
    }
    __syncthreads();

    // out = gamma*(O/l)@Wv + x ; wave owns 4 rows, lane owns 4 cols.
    // float4 LDS reads: Os rows (wave-uniform broadcast) + wv col-slices.
    const float g   = gamma[0];
    const int   ec0 = lane * 4;
    const int  erow = base + n0 + wave * 4;
    float4 acc4[4];
    #pragma unroll
    for (int rr = 0; rr < 4; ++rr) acc4[rr] = (float4){0.f, 0.f, 0.f, 0.f};
    for (int d4 = 0; d4 < 32; d4 += 4) {
        float4 w0 = *reinterpret_cast<const float4*>(&wv[(d4 + 0) * 256 + ec0]);
        float4 w1 = *reinterpret_cast<const float4*>(&wv[(d4 + 1) * 256 + ec0]);
        float4 w2 = *reinterpret_cast<const float4*>(&wv[(d4 + 2) * 256 + ec0]);
        float4 w3 = *reinterpret_cast<const float4*>(&wv[(d4 + 3) * 256 + ec0]);
        #pragma unroll
        for (int rr = 0; rr < 4; ++rr) {
            float4 ov = *reinterpret_cast<const float4*>(&Os[wave * 4 + rr][d4]);
            acc4[rr].x += ov.x * w0.x + ov.y * w1.x + ov.z * w2.x + ov.w * w3.x;
            acc4[rr].y += ov.x * w0.y + ov.y * w1.y + ov.z * w2.y + ov.w * w3.y;
            acc4[rr].z += ov.x * w0.z + ov.y * w1.z + ov.z * w2.z + ov.w * w3.z;
            acc4[rr].w += ov.x * w0.w + ov.y * w1.w + ov.z * w2.w + ov.w * w3.w;
        }
    }
    #pragma unroll
    for (int rr = 0; rr < 4; ++rr) {
        float gl = g * linv[wave * 4 + rr];
        float4 xr = *reinterpret_cast<const float4*>(&x[(erow + rr) * 256 + ec0]);
        float4 r;
        r.x = gl * acc4[rr].x + xr.x;
        r.y = gl * acc4[rr].y + xr.y;
        r.z = gl * acc4[rr].z + xr.z;
        r.w = gl * acc4[rr].w + xr.w;
        *reinterpret_cast<float4*>(&out[(erow + rr) * 256 + ec0]) = r;
    }
}

extern "C" void kernel_launch(void* const* d_in, const int* in_sizes, int n_in,
                              void* d_out, int out_size, void* d_ws, size_t ws_size,
                              hipStream_t stream)
{
    const float* x     = (const float*)d_in[0];
    const float* Wf    = (const float*)d_in[1];
    const float* Wg    = (const float*)d_in[2];
    const float* Wh    = (const float*)d_in[3];
    const float* Wv    = (const float*)d_in[4];
    const float* gamma = (const float*)d_in[5];
    float* out = (float*)d_out;

    // ws: qh (fp16), kf (fp16), vT (bf16) — 1 MB each
    ushort_t* qh = (ushort_t*)d_ws;
    ushort_t* kf = qh + NROWS * 32;
    ushort_t* vT = kf + NROWS * 32;

    qkv_kernel<<<dim3(512), dim3(256), 0, stream>>>(x, Wf, Wg, Wh, qh, kf, vT);
    attn_kernel<<<dim3(256), dim3(1024), 0, stream>>>(qh, kf, vT, Wv, x, gamma, out);
}

// Round 8
// 113.450 us; speedup vs baseline: 1.3228x; 1.3228x over previous
//
#include <hip/hip_runtime.h>
#include <hip/hip_bf16.h>
#include <stdint.h>

// NonLocalBlock, fp32 in/out. B=4, N=4096, C=256, D=32.
// v14 == v10 (best-known state, 112.1 us). Reverts v12/v13's float4 epilogue:
// the quad-aligned register demand (acc4/w0-w3/ov/xr as float4s) pushed peak
// pressure past the allocator's 64-VGPR point -> ~100 MB scratch spill
// traffic, attn 5x slower (v13: FETCH 97 MB / WRITE 115 MB). v10's scalar
// epilogue runs clean (v11 evidence: FETCH 25 / WRITE 19 MB @ 60 VGPR).
// Main loop: fp16 q/k, ONE mfma_f32_16x16x32_f16 for S^T, bf16 P/V,
// barrier-free, register-resident. ~88 us of dur is harness ws-poison fill.

typedef __attribute__((ext_vector_type(8))) short bf16x8;
typedef __attribute__((ext_vector_type(4))) short bf16x4;
typedef __attribute__((ext_vector_type(8))) _Float16 f16x8;
typedef __attribute__((ext_vector_type(4))) float f32x4;
typedef unsigned short ushort_t;

static __device__ __forceinline__ ushort_t f2bf(float f) {
    __hip_bfloat16 h = __float2bfloat16(f);
    return __builtin_bit_cast(ushort_t, h);
}
static __device__ __forceinline__ float bf2f(ushort_t u) {
    return __bfloat162float(__builtin_bit_cast(__hip_bfloat16, u));
}
static __device__ __forceinline__ ushort_t f2h(float f) {
    _Float16 h = (_Float16)f;            // RNE v_cvt_f16_f32
    return __builtin_bit_cast(ushort_t, h);
}
// truncation split: hi = top 16 bits (no rounding), residual w-hi is exact,
// lo = RNE bf16 of residual.
static __device__ __forceinline__ void tsplit(float w, ushort_t& hi, ushort_t& lo) {
    uint32_t b = __builtin_bit_cast(uint32_t, w);
    hi = (ushort_t)(b >> 16);
    float hf = __builtin_bit_cast(float, b & 0xFFFF0000u);
    lo = f2bf(w - hf);
}

static __device__ __forceinline__ f32x4 mfma16bf(bf16x4 a, bf16x4 b, f32x4 c) {
#if __has_builtin(__builtin_amdgcn_mfma_f32_16x16x16bf16_1k)
    return __builtin_amdgcn_mfma_f32_16x16x16bf16_1k(a, b, c, 0, 0, 0);
#else
    f32x4 d;
    asm("v_mfma_f32_16x16x16_bf16 %0, %1, %2, %3"
        : "=v"(d) : "v"(a), "v"(b), "v"(c));
    return d;
#endif
}

static __device__ __forceinline__ float fexp2(float x) {
#if __has_builtin(__builtin_amdgcn_exp2f)
    return __builtin_amdgcn_exp2f(x);
#else
    return exp2f(x);
#endif
}

#define NROWS 16384
#define NTOK  4096
#define QKS   40   // x-staging LDS row stride (ushorts): 80 B, 16B-aligned
#define LOG2E 1.44269504088896340736f

// ---------------- K1: QKV projection via split-bf16 MFMA ----------------
// 32 rows/block, grid 512 (2 blocks/CU). Wave w: row-group w&1, col-groups
// (w>>1)+{0,2,4}. W fp32 read per-lane (L1/L2-hot), truncation-split in regs.
// q output pre-scaled by log2(e); q and k stored fp16, v bf16 transposed.
__global__ __launch_bounds__(256) void qkv_kernel(
    const float* __restrict__ x,
    const float* __restrict__ Wf, const float* __restrict__ Wg,
    const float* __restrict__ Wh,
    ushort_t* __restrict__ qh,   // fp16 [b*n][32], pre-scaled by log2(e)
    ushort_t* __restrict__ kf,   // fp16 [b*n][32]
    ushort_t* __restrict__ vT)   // bf16 [b][d][m] = [4][32][4096]
{
    __shared__ __align__(16) ushort_t xh[32 * QKS];
    __shared__ __align__(16) ushort_t xl[32 * QKS];

    const int tid  = threadIdx.x;
    const int wave = tid >> 6;
    const int lane = tid & 63;
    const int ln15 = lane & 15;
    const int quad = lane >> 4;
    const int row0 = blockIdx.x * 32;
    const int rg     = wave & 1;
    const int cgbase = wave >> 1;
    const int r  = tid >> 3;        // staging row 0..31
    const int pp = (tid & 7) * 4;   // staging col (floats)

    f32x4 acc[3];
    #pragma unroll
    for (int ci = 0; ci < 3; ++ci) acc[ci] = (f32x4){0.f, 0.f, 0.f, 0.f};

    float4 xa = *reinterpret_cast<const float4*>(&x[(row0 + r) * 256 + pp]);

    for (int k0 = 0; k0 < 256; k0 += 32) {
        // B fragments: read W fp32 directly, truncation-split in registers
        bf16x8 bh[3], bl[3];
        #pragma unroll
        for (int ci = 0; ci < 3; ++ci) {
            int cg = cgbase + ci * 2;
            const float* Wsrc = (cg < 2) ? Wf : (cg < 4) ? Wg : Wh;
            int c = (cg & 1) * 16 + ln15;
            ushort_t hv8[8], lv8[8];
            #pragma unroll
            for (int j = 0; j < 8; ++j) {
                float w = Wsrc[(k0 + quad * 8 + j) * 32 + c];
                tsplit(w, hv8[j], lv8[j]);
            }
            bh[ci] = *reinterpret_cast<bf16x8*>(hv8);
            bl[ci] = *reinterpret_cast<bf16x8*>(lv8);
        }
        // split current x chunk
        float fv[4];
        *reinterpret_cast<float4*>(fv) = xa;
        ushort_t hv[4], lv[4];
        #pragma unroll
        for (int j = 0; j < 4; ++j) tsplit(fv[j], hv[j], lv[j]);
        __syncthreads();
        *reinterpret_cast<uint2*>(&xh[r * QKS + pp]) = *reinterpret_cast<uint2*>(hv);
        *reinterpret_cast<uint2*>(&xl[r * QKS + pp]) = *reinterpret_cast<uint2*>(lv);
        __syncthreads();
        if (k0 < 224)
            xa = *reinterpret_cast<const float4*>(&x[(row0 + r) * 256 + k0 + 32 + pp]);

        const bf16x8 ah = *reinterpret_cast<const bf16x8*>(
            &xh[(rg * 16 + ln15) * QKS + quad * 8]);
        const bf16x8 al = *reinterpret_cast<const bf16x8*>(
            &xl[(rg * 16 + ln15) * QKS + quad * 8]);
        #pragma unroll
        for (int ci = 0; ci < 3; ++ci) {
            acc[ci] = __builtin_amdgcn_mfma_f32_16x16x32_bf16(ah, bh[ci], acc[ci], 0, 0, 0);
            acc[ci] = __builtin_amdgcn_mfma_f32_16x16x32_bf16(al, bh[ci], acc[ci], 0, 0, 0);
            acc[ci] = __builtin_amdgcn_mfma_f32_16x16x32_bf16(ah, bl[ci], acc[ci], 0, 0, 0);
        }
    }

    #pragma unroll
    for (int ci = 0; ci < 3; ++ci) {
        int cg = cgbase + ci * 2;
        int cc = (cg & 1) * 16 + ln15;
        int rowb = row0 + rg * 16 + quad * 4;
        if (cg < 2) {
            #pragma unroll
            for (int rr = 0; rr < 4; ++rr)
                qh[(rowb + rr) * 32 + cc] = f2h(acc[ci][rr] * LOG2E);
        } else if (cg < 4) {
            #pragma unroll
            for (int rr = 0; rr < 4; ++rr)
                kf[(rowb + rr) * 32 + cc] = f2h(acc[ci][rr]);
        } else {
            // V pre-transposed: vT[b][d=cc][m], m = rowb..rowb+3 (same batch)
            int bb = row0 >> 12;
            int m  = (row0 & 4095) + rg * 16 + quad * 4;
            ushort4 h4;
            h4.x = f2bf(acc[ci][0]);
            h4.y = f2bf(acc[ci][1]);
            h4.z = f2bf(acc[ci][2]);
            h4.w = f2bf(acc[ci][3]);
            *reinterpret_cast<ushort4*>(&vT[bb * 131072 + cc * 4096 + m]) = h4;
        }
    }
}

// ---------------- K2: fused attention + output projection ----------------
// Grid 256 = 4 batches x 64 rowtiles, 1024 threads (16 waves, 4 waves/SIMD).
// Wave w owns m-sub 16 of each 256-m iter, 16 iters (full m range). Per wave:
//   K frags (4 n-tiles, fp16) in regs, loaded once.
//   S^T[m',n] = one mfma_16x16x32_f16(A=Q, B=K): lane holds P^T[m'][n=ln15].
//   p = exp2(s) (q pre-scaled by log2e) -> bf16 -> B-frag of 16x16x16 PV MFMA:
//   O^T[d,n] += V^T[d,m'] * P^T[m',n], V^T A-frags as 8 B loads from vT.
// Next-iter Q/V prefetched into regs. No LDS / no barriers in the loop.
// Epilogue: waves 0-7 write Ored/Lred, waves 8-15 accumulate into the same
// slots, then 1/l and out = gamma*(O/l)@Wv + x (scalar form — float4 retile
// spills at the 64-VGPR operating point, v12/v13 post-mortem).
__global__ __launch_bounds__(1024, 4) void attn_kernel(
    const ushort_t* __restrict__ qhg,
    const ushort_t* __restrict__ kfg,
    const ushort_t* __restrict__ vT,
    const float* __restrict__ Wv, const float* __restrict__ x,
    const float* __restrict__ gamma, float* __restrict__ out)
{
    __shared__ float Ored[8][32][65];   // [slot][d][n], stride 65
    __shared__ float Lred[8][64];
    __shared__ float wv[8192];          // Wv [32][256]
    __shared__ float Os[64][33];        // O [n][d]
    __shared__ float linv[64];

    const int tid  = threadIdx.x;
    const int wave = tid >> 6;          // 0..15
    const int lane = tid & 63;
    const int ln15 = lane & 15;
    const int quad = lane >> 4;

    const int b    = blockIdx.x >> 6;
    const int n0   = (blockIdx.x & 63) * 64;
    const int base = b * NTOK;
    const int bb   = b * 131072;        // vT batch offset

    // K fragments in registers (B-operand of S^T): K[n=t*16+ln15][c=quad*8..+7]
    f16x8 khf[4];
    #pragma unroll
    for (int t = 0; t < 4; ++t)
        khf[t] = *reinterpret_cast<const f16x8*>(
            &kfg[(base + n0 + t * 16 + ln15) * 32 + quad * 8]);

    // stage Wv while the main loop runs (no barrier until epilogue)
    #pragma unroll
    for (int i = 0; i < 8; ++i) wv[tid + i * 1024] = Wv[tid + i * 1024];

    f32x4 accO[2][4];   // [s01 = d-tile][t = n-tile]
    #pragma unroll
    for (int s01 = 0; s01 < 2; ++s01)
        #pragma unroll
        for (int t = 0; t < 4; ++t)
            accO[s01][t] = (f32x4){0.f, 0.f, 0.f, 0.f};
    float lacc[4] = {0.f, 0.f, 0.f, 0.f};

    // per-wave m walk: m = it*256 + wave*16 + {0..15}, it = 0..15
    const int mbase = wave * 16;
    const ushort_t* qp  = qhg + (size_t)(base + mbase + ln15) * 32 + quad * 8;
    const ushort_t* vp0 = vT + bb + ln15 * 4096 + mbase + quad * 4;
    const ushort_t* vp1 = vp0 + 16 * 4096;

    f16x8  qf  = *reinterpret_cast<const f16x8*>(qp);    // A: Q[m=ln15][c]
    bf16x4 va0 = *reinterpret_cast<const bf16x4*>(vp0);  // A: V^T[d=ln15][m']
    bf16x4 va1 = *reinterpret_cast<const bf16x4*>(vp1);  // A: V^T[d=16+ln15][m']

    for (int it = 0; it < 16; ++it) {
        qp  += 256 * 32;
        vp0 += 256;
        vp1 += 256;
        // prefetch next iter (it=15 reads past the 3 MB region but stays well
        // inside the 256 MB workspace; values unused)
        f16x8  nqf  = *reinterpret_cast<const f16x8*>(qp);
        bf16x4 nva0 = *reinterpret_cast<const bf16x4*>(vp0);
        bf16x4 nva1 = *reinterpret_cast<const bf16x4*>(vp1);

        #pragma unroll
        for (int t = 0; t < 4; ++t) {
            // S^T[m'][n] for n-tile t; lane: m'=quad*4+rr, n=t*16+ln15
            f32x4 s = __builtin_amdgcn_mfma_f32_16x16x32_f16(
                qf, khf[t], (f32x4){0.f, 0.f, 0.f, 0.f}, 0, 0, 0);

            float p0 = fexp2(s[0]);
            float p1 = fexp2(s[1]);
            float p2 = fexp2(s[2]);
            float p3 = fexp2(s[3]);
            lacc[t] += (p0 + p1) + (p2 + p3);

            ushort_t pu[4];
            pu[0] = f2bf(p0);
            pu[1] = f2bf(p1);
            pu[2] = f2bf(p2);
            pu[3] = f2bf(p3);
            const bf16x4 pb = *reinterpret_cast<bf16x4*>(pu);  // B: P^T[m'][n]

            accO[0][t] = mfma16bf(va0, pb, accO[0][t]);
            accO[1][t] = mfma16bf(va1, pb, accO[1][t]);
        }
        qf = nqf; va0 = nva0; va1 = nva1;
    }

    // ---- cross-wave reduction ----
    // lane holds O^T[d = s01*16 + quad*4 + rr][n = t*16 + ln15]
    float lr[4];
    #pragma unroll
    for (int t = 0; t < 4; ++t) {
        float v = lacc[t];
        v += __shfl_xor(v, 16);
        v += __shfl_xor(v, 32);
        lr[t] = v;
    }
    if (wave < 8) {
        #pragma unroll
        for (int s01 = 0; s01 < 2; ++s01)
            #pragma unroll
            for (int t = 0; t < 4; ++t)
                #pragma unroll
                for (int rr = 0; rr < 4; ++rr)
                    Ored[wave][s01 * 16 + quad * 4 + rr][t * 16 + ln15] = accO[s01][t][rr];
        if (quad == 0) {
            #pragma unroll
            for (int t = 0; t < 4; ++t) Lred[wave][t * 16 + ln15] = lr[t];
        }
    }
    __syncthreads();
    if (wave >= 8) {
        const int ws = wave - 8;
        #pragma unroll
        for (int s01 = 0; s01 < 2; ++s01)
            #pragma unroll
            for (int t = 0; t < 4; ++t)
                #pragma unroll
                for (int rr = 0; rr < 4; ++rr)
                    Ored[ws][s01 * 16 + quad * 4 + rr][t * 16 + ln15] += accO[s01][t][rr];
        if (quad == 0) {
            #pragma unroll
            for (int t = 0; t < 4; ++t) Lred[ws][t * 16 + ln15] += lr[t];
        }
    }
    __syncthreads();

    // O[n][d] = sum over 8 slots; 1/l
    #pragma unroll
    for (int i = 0; i < 2; ++i) {
        int idx = i * 1024 + tid;     // 0..2047
        int d = idx & 31;
        int n = idx >> 5;
        float v = (Ored[0][d][n] + Ored[1][d][n]) + (Ored[2][d][n] + Ored[3][d][n])
                + (Ored[4][d][n] + Ored[5][d][n]) + (Ored[6][d][n] + Ored[7][d][n]);
        Os[n][d] = v;
    }
    if (tid < 64) {
        float s = (Lred[0][tid] + Lred[1][tid]) + (Lred[2][tid] + Lred[3][tid])
                + (Lred[4][tid] + Lred[5][tid]) + (Lred[6][tid] + Lred[7][tid]);
        linv[tid] = 1.0f / s;
    }
    __syncthreads();

    // out = gamma*(O/l)@Wv + x ; thread owns col c, 16 rows
    const float g  = gamma[0];
    const int   c  = tid & 255;
    const int   nh = (tid >> 8) * 16;
    const int rowb = base + n0 + nh;
    #pragma unroll
    for (int rc = 0; rc < 16; rc += 8) {
        float acc[8];
        #pragma unroll
        for (int rr = 0; rr < 8; ++rr) acc[rr] = 0.f;
        for (int d = 0; d < 32; ++d) {
            float wvd = wv[d * 256 + c];
            #pragma unroll
            for (int rr = 0; rr < 8; ++rr) acc[rr] += Os[nh + rc + rr][d] * wvd;
        }
        #pragma unroll
        for (int rr = 0; rr < 8; ++rr) {
            int row = rowb + rc + rr;
            out[row * 256 + c] = g * acc[rr] * linv[nh + rc + rr] + x[row * 256 + c];
        }
    }
}

extern "C" void kernel_launch(void* const* d_in, const int* in_sizes, int n_in,
                              void* d_out, int out_size, void* d_ws, size_t ws_size,
                              hipStream_t stream)
{
    const float* x     = (const float*)d_in[0];
    const float* Wf    = (const float*)d_in[1];
    const float* Wg    = (const float*)d_in[2];
    const float* Wh    = (const float*)d_in[3];
    const float* Wv    = (const float*)d_in[4];
    const float* gamma = (const float*)d_in[5];
    float* out = (float*)d_out;

    // ws: qh (fp16), kf (fp16), vT (bf16) — 1 MB each
    ushort_t* qh = (ushort_t*)d_ws;
    ushort_t* kf = qh + NROWS * 32;
    ushort_t* vT = kf + NROWS * 32;

    qkv_kernel<<<dim3(512), dim3(256), 0, stream>>>(x, Wf, Wg, Wh, qh, kf, vT);
    attn_kernel<<<dim3(256), dim3(1024), 0, stream>>>(qh, kf, vT, Wv, x, gamma, out);
}